// Round 6
// baseline (1211.039 us; speedup 1.0000x reference)
//
#include <hip/hip_runtime.h>

typedef unsigned short u16;
typedef unsigned int   u32;
typedef __attribute__((ext_vector_type(8))) short bf16x8;   // 8 bf16 (4 VGPRs)
typedef __attribute__((ext_vector_type(4))) float f32x4;    // mfma acc

#define EPS 1e-5f
#define MFMA(a,b,c) __builtin_amdgcn_mfma_f32_16x16x32_bf16(a,b,c,0,0,0)
#define NBLK 768   // 3 blocks/CU x 256 CUs — co-residency proven by R4/R5 occupancy

__device__ __forceinline__ float bf2f(u32 u) { return __uint_as_float(u << 16); }
__device__ __forceinline__ u16 f2bf(float f) {
  u32 b = __float_as_uint(f);
  return (u16)((b + 0x7fffu + ((b >> 16) & 1u)) >> 16);  // RNE
}
__device__ __forceinline__ u32 fkey(float f) {  // monotone float->u32 (finite)
  u32 b = __float_as_uint(f);
  return (b & 0x80000000u) ? ~b : (b | 0x80000000u);
}

// ---- device-scope grid barrier (bar[0]=arrive, bar[1]=generation; pre-zeroed) ----
__device__ __forceinline__ void gbar(u32* bar) {
  __syncthreads();
  if (threadIdx.x == 0) {
    u32 gen = __hip_atomic_load(&bar[1], __ATOMIC_ACQUIRE, __HIP_MEMORY_SCOPE_AGENT);
    __threadfence();
    u32 prev = __hip_atomic_fetch_add(&bar[0], 1u, __ATOMIC_ACQ_REL, __HIP_MEMORY_SCOPE_AGENT);
    if (prev == (u32)gridDim.x - 1u) {
      __hip_atomic_store(&bar[0], 0u, __ATOMIC_RELAXED, __HIP_MEMORY_SCOPE_AGENT);
      __hip_atomic_store(&bar[1], gen + 1u, __ATOMIC_RELEASE, __HIP_MEMORY_SCOPE_AGENT);
    } else {
      while (__hip_atomic_load(&bar[1], __ATOMIC_ACQUIRE, __HIP_MEMORY_SCOPE_AGENT) == gen)
        __builtin_amdgcn_s_sleep(8);
    }
    __threadfence();
  }
  __syncthreads();
}

// B-frag swizzle element: frag f, lane L, j -> W[(f>>2)*32+((L>>4)<<3)+j][((f&3)<<4)+(L&15)]
__device__ __forceinline__ u16 swz(const float* __restrict__ W, int idx) {
  int f = idx >> 9, L = (idx >> 3) & 63, j = idx & 7;
  int k = (f >> 2) * 32 + ((L >> 4) << 3) + j, n = ((f & 3) << 4) + (L & 15);
  return f2bf(W[k * 64 + n]);
}

struct Args {
  const float *X, *te;
  const float *W1, *b1, *g1, *be1, *W2, *b2, *rel_emb;
  const float *Wm1, *bm1, *Wm2, *bm2, *gn, *bn, *Wg1, *bg1, *Wg2, *bg2;
  float* out;
  u32* bar; float* gsum; u32* gmax; u32* counts; float* agg;   // zeroed by memset
  u32* cursor; u32* partial; u16* gfr; uint4* tes; u16* hb;    // written before read
  int N, E;
};

// global frag layout: gW1[16384] | gW2[4096] | gWm1[12288] | gWm2[4096] | grel[576]
constexpr int GF_W1 = 0, GF_W2 = 16384, GF_Wm1 = 20480, GF_Wm2 = 32768, GF_rel = 36864,
              GF_TOT = 37440;

__launch_bounds__(256, 3)
__global__ void k_mega(Args a) {
  __shared__ __align__(16) u16 uW[20480];     // 40 KB phase-union
  __shared__ __align__(16) u16 st[4][1152];   // 9 KB transpose buffers
  const int tid = threadIdx.x;
  const int gtid = blockIdx.x * 256 + tid;
  const int nth = gridDim.x * 256;
  const int lane = tid & 63, wave = tid >> 6;
  const int m = lane & 15, quad = lane >> 4, koff = quad * 8, col0 = m;
  const int wid = blockIdx.x * 4 + wave, nw = gridDim.x * 4;

  // ---------------- P0: swizzle all MFMA weights into global frag buffer ----------------
  for (int i = gtid; i < 16384; i += nth) a.gfr[GF_W1 + i] = swz(a.W1, i);
  for (int i = gtid; i < 4096; i += nth)  a.gfr[GF_W2 + i] = swz(a.W2, i);
  for (int i = gtid; i < 12288; i += nth) a.gfr[GF_Wm1 + i] = swz(a.Wm1, i);
  for (int i = gtid; i < 4096; i += nth)  a.gfr[GF_Wm2 + i] = swz(a.Wm2, i);
  for (int i = gtid; i < 576; i += nth) {
    int r = i / 80, c = i % 80;
    a.gfr[GF_rel + i] = (r < 7 && c < 64) ? f2bf(a.rel_emb[r * 64 + c]) : (u16)0;
  }
  gbar(a.bar);

  // ---------------- P1: h = relu(relu(LN(X@W1+b1))@W2+b2) -> bf16 ; + dst histogram ----
  {
    const uint4* srcp = (const uint4*)(a.gfr + GF_W1);
    uint4* d1 = (uint4*)uW;
    for (int i = tid; i < 2560; i += 256) d1[i] = srcp[i];   // W1+W2 frags contiguous
    __syncthreads();
    const u16* sW1 = uW;
    const u16* sW2 = uW + 16384;

    float b1v[4], g1v[4], be1v[4], b2v[4];
    #pragma unroll
    for (int nt = 0; nt < 4; nt++) {
      int c = nt * 16 + col0;
      b1v[nt] = a.b1[c]; g1v[nt] = a.g1[c]; be1v[nt] = a.be1[c]; b2v[nt] = a.b2[c];
    }

    int ntiles = (a.N + 15) / 16;
    for (int tile = wid; tile < ntiles; tile += nw) {
      int n0 = tile * 16;
      int nm = min(n0 + m, a.N - 1);
      const float* xr = a.X + (size_t)nm * 256 + koff;

      f32x4 acc[4] = {};
      #pragma unroll 4
      for (int ks = 0; ks < 8; ks++) {
        float4 u0 = *(const float4*)(xr + ks * 32);
        float4 u1 = *(const float4*)(xr + ks * 32 + 4);
        bf16x8 av;
        av[0] = (short)f2bf(u0.x); av[1] = (short)f2bf(u0.y);
        av[2] = (short)f2bf(u0.z); av[3] = (short)f2bf(u0.w);
        av[4] = (short)f2bf(u1.x); av[5] = (short)f2bf(u1.y);
        av[6] = (short)f2bf(u1.z); av[7] = (short)f2bf(u1.w);
        #pragma unroll
        for (int nt = 0; nt < 4; nt++) {
          bf16x8 b = *(const bf16x8*)(sW1 + (ks * 4 + nt) * 512 + lane * 8);
          acc[nt] = MFMA(av, b, acc[nt]);
        }
      }

      float v[4][4];
      #pragma unroll
      for (int nt = 0; nt < 4; nt++)
        #pragma unroll
        for (int r = 0; r < 4; r++) v[nt][r] = acc[nt][r] + b1v[nt];

      #pragma unroll
      for (int r = 0; r < 4; r++) {
        float s = v[0][r] + v[1][r] + v[2][r] + v[3][r];
        #pragma unroll
        for (int mk = 8; mk >= 1; mk >>= 1) s += __shfl_xor(s, mk, 64);
        float mu = s * (1.f / 64.f);
        float q = 0.f;
        #pragma unroll
        for (int nt = 0; nt < 4; nt++) { float d = v[nt][r] - mu; q += d * d; }
        #pragma unroll
        for (int mk = 8; mk >= 1; mk >>= 1) q += __shfl_xor(q, mk, 64);
        float rs = rsqrtf(q * (1.f / 64.f) + EPS);
        #pragma unroll
        for (int nt = 0; nt < 4; nt++) {
          float h1 = fmaxf(fmaf((v[nt][r] - mu) * rs, g1v[nt], be1v[nt]), 0.f);
          st[wave][(quad * 4 + r) * 72 + nt * 16 + col0] = f2bf(h1);
        }
      }
      __builtin_amdgcn_wave_barrier();

      f32x4 acc2[4] = {};
      #pragma unroll
      for (int ks = 0; ks < 2; ks++) {
        bf16x8 a2 = *(const bf16x8*)(st[wave] + m * 72 + ks * 32 + koff);
        #pragma unroll
        for (int nt = 0; nt < 4; nt++) {
          bf16x8 b = *(const bf16x8*)(sW2 + (ks * 4 + nt) * 512 + lane * 8);
          acc2[nt] = MFMA(a2, b, acc2[nt]);
        }
      }
      __builtin_amdgcn_wave_barrier();

      #pragma unroll
      for (int nt = 0; nt < 4; nt++)
        #pragma unroll
        for (int r = 0; r < 4; r++) {
          int row = n0 + quad * 4 + r;
          if (row < a.N)
            a.hb[(size_t)row * 64 + nt * 16 + col0] = f2bf(fmaxf(acc2[nt][r] + b2v[nt], 0.f));
        }
    }

    // dst histogram
    for (int e = gtid; e < a.E; e += nth) {
      float dv = a.te[(size_t)e * 4 + 1];
      int d = min(max((int)dv, 0), a.N - 1);
      atomicAdd(&a.counts[d], 1u);
    }
  }
  gbar(a.bar);

  // ---------------- P2a: per-block chunk sums of counts ----------------
  u32* s32 = (u32*)uW;
  const int CH = (a.N + gridDim.x - 1) / gridDim.x;   // 131 for N=100000
  const int lo = blockIdx.x * CH;
  {
    u32 s = 0;
    for (int i = lo + tid; i < min(lo + CH, a.N); i += 256) s += a.counts[i];
    s32[tid] = s; __syncthreads();
    for (int off = 128; off > 0; off >>= 1) {
      if (tid < off) s32[tid] += s32[tid + off];
      __syncthreads();
    }
    if (tid == 0) a.partial[blockIdx.x] = s32[0];
  }
  gbar(a.bar);

  // ---------------- P2c: base reduce + chunk exclusive scan -> cursor ----------------
  {
    u32 s = 0;
    for (int i = tid; i < (int)gridDim.x; i += 256)
      if (i < (int)blockIdx.x) s += a.partial[i];
    s32[tid] = s; __syncthreads();
    for (int off = 128; off > 0; off >>= 1) {
      if (tid < off) s32[tid] += s32[tid + off];
      __syncthreads();
    }
    u32 base = s32[0];
    __syncthreads();
    // chunk scan (CH <= 256)
    u32* sc = s32 + 256;
    int i = lo + tid;
    u32 c = (tid < CH && i < a.N) ? a.counts[i] : 0u;
    sc[tid] = c; __syncthreads();
    for (int off = 1; off < 256; off <<= 1) {
      u32 v = (tid >= off) ? sc[tid - off] : 0u;
      __syncthreads();
      sc[tid] += v;
      __syncthreads();
    }
    if (tid < CH && i < a.N) a.cursor[i] = base + sc[tid] - c;
  }
  gbar(a.bar);

  // ---------------- P3: scatter edges into dst-sorted tes ----------------
  for (int e = gtid; e < a.E; e += nth) {
    float4 v = *(const float4*)(a.te + (size_t)e * 4);
    int s = min(max((int)v.x, 0), a.N - 1);
    int d = min(max((int)v.y, 0), a.N - 1);
    int r = min(max((int)v.z, 0), 6);
    u32 pos = atomicAdd(&a.cursor[d], 1u);
    a.tes[pos] = make_uint4((u32)s, (u32)d, (u32)r, __float_as_uint(v.w));
  }
  gbar(a.bar);

  // ---------------- P4: edge MLP (MFMA) + segmented reduce into agg ----------------
  {
    const uint4* srcp = (const uint4*)(a.gfr + GF_Wm1);
    uint4* d1 = (uint4*)uW;
    for (int i = tid; i < 2120; i += 256) d1[i] = srcp[i];   // Wm1+Wm2+rel contiguous
    __syncthreads();
    const u16* sWm1 = uW;
    const u16* sWm2 = uW + 12288;
    const u16* srel = uW + 16384;

    float bm1v[4], w192v[4], bm2v[4];
    #pragma unroll
    for (int nt = 0; nt < 4; nt++) {
      int c = nt * 16 + col0;
      bm1v[nt] = a.bm1[c];
      w192v[nt] = a.Wm1[192 * 64 + c];
      bm2v[nt] = a.bm2[c];
    }

    int nranges = (a.E + 127) / 128;
    for (int range = wid; range < nranges; range += nw) {
      int r0 = range * 128;
      int run_dst = -2;
      float run = 0.f;
      bool bs = false;

      #pragma unroll 1
      for (int t8 = 0; t8 < 8; t8++) {
        int p0 = r0 + t8 * 16;
        if (p0 >= a.E) break;

        int src = 0, dstc = 0, rel = 0, dtag = -1; float w = 0.f;
        if (lane < 16) {
          int p = p0 + lane;
          if (p < a.E) {
            uint4 v = a.tes[p];
            src = (int)v.x; dstc = (int)v.y; rel = (int)v.z;
            w = __uint_as_float(v.w);
            dtag = dstc;
          }
        }
        int src_m = __shfl(src, m, 64);
        int dst_m = __shfl(dstc, m, 64);
        int rel_m = __shfl(rel, m, 64);

        const u16* hs = a.hb + (size_t)src_m * 64;
        const u16* hd = a.hb + (size_t)dst_m * 64;
        bf16x8 af[6];
        af[0] = *(const bf16x8*)(hs + koff);
        af[1] = *(const bf16x8*)(hs + 32 + koff);
        af[2] = *(const bf16x8*)(hd + koff);
        af[3] = *(const bf16x8*)(hd + 32 + koff);
        af[4] = *(const bf16x8*)(srel + rel_m * 80 + koff);
        af[5] = *(const bf16x8*)(srel + rel_m * 80 + 32 + koff);

        f32x4 acc[4] = {};
        #pragma unroll
        for (int ks = 0; ks < 6; ks++) {
          #pragma unroll
          for (int nt = 0; nt < 4; nt++) {
            bf16x8 b = *(const bf16x8*)(sWm1 + (ks * 4 + nt) * 512 + lane * 8);
            acc[nt] = MFMA(af[ks], b, acc[nt]);
          }
        }

        float wrow[4];
        #pragma unroll
        for (int r = 0; r < 4; r++) wrow[r] = __shfl(w, quad * 4 + r, 64);
        #pragma unroll
        for (int nt = 0; nt < 4; nt++)
          #pragma unroll
          for (int r = 0; r < 4; r++) {
            float v = fmaf(wrow[r], w192v[nt], acc[nt][r] + bm1v[nt]);
            st[wave][(quad * 4 + r) * 72 + nt * 16 + col0] = f2bf(fmaxf(v, 0.f));
          }
        __builtin_amdgcn_wave_barrier();

        f32x4 acc2[4] = {};
        #pragma unroll
        for (int ks = 0; ks < 2; ks++) {
          bf16x8 a2 = *(const bf16x8*)(st[wave] + m * 72 + ks * 32 + koff);
          #pragma unroll
          for (int nt = 0; nt < 4; nt++) {
            bf16x8 b = *(const bf16x8*)(sWm2 + (ks * 4 + nt) * 512 + lane * 8);
            acc2[nt] = MFMA(a2, b, acc2[nt]);
          }
        }
        __builtin_amdgcn_wave_barrier();

        #pragma unroll
        for (int nt = 0; nt < 4; nt++)
          #pragma unroll
          for (int r = 0; r < 4; r++)
            st[wave][(quad * 4 + r) * 72 + nt * 16 + col0] =
                f2bf(acc2[nt][r] + bm2v[nt]);
        __builtin_amdgcn_wave_barrier();

        #pragma unroll 1
        for (int r = 0; r < 16; r++) {
          int d = __shfl(dtag, r, 64);
          float val = bf2f(st[wave][r * 72 + lane]);
          if (d != run_dst) {
            if (run_dst >= 0) {
              float* ap = a.agg + (size_t)run_dst * 64 + lane;
              if (bs) atomicAdd(ap, run); else *ap = run;
            }
            run_dst = d; run = val; bs = (t8 == 0 && r == 0);
          } else {
            run += val;
          }
        }
        __builtin_amdgcn_wave_barrier();
      }
      if (run_dst >= 0) atomicAdd(a.agg + (size_t)run_dst * 64 + lane, run);
    }
  }
  gbar(a.bar);

  // ---------------- P5: nodes = LN(h+agg); column sum + max ----------------
  {
    float* bs = (float*)uW;          // 256
    float* bm = (float*)uW + 256;    // 256
    float gnv = a.gn[lane], bnv = a.bn[lane];
    float sj = 0.f, mj = -3.0e38f;
    for (int n = wid; n < a.N; n += nw) {
      float v = bf2f(a.hb[(size_t)n * 64 + lane]) + a.agg[(size_t)n * 64 + lane];
      float s = v;
      #pragma unroll
      for (int mk = 32; mk >= 1; mk >>= 1) s += __shfl_xor(s, mk, 64);
      float mu = s * (1.f / 64.f);
      float d = v - mu;
      float q = d * d;
      #pragma unroll
      for (int mk = 32; mk >= 1; mk >>= 1) q += __shfl_xor(q, mk, 64);
      float rs = rsqrtf(q * (1.f / 64.f) + EPS);
      float val = fmaf(d * rs, gnv, bnv);
      sj += val;
      mj = fmaxf(mj, val);
    }
    bs[tid] = sj;
    bm[tid] = mj;
    __syncthreads();
    if (tid < 64) {
      float ts = bs[tid] + bs[64 + tid] + bs[128 + tid] + bs[192 + tid];
      float tm = fmaxf(fmaxf(bm[tid], bm[64 + tid]), fmaxf(bm[128 + tid], bm[192 + tid]));
      atomicAdd(a.gsum + tid, ts);
      atomicMax(a.gmax + tid, fkey(tm));
    }
  }
  gbar(a.bar);

  // ---------------- P6: block 0 runs the final tiny MLP ----------------
  if (blockIdx.x == 0) {
    float* g = (float*)uW;          // 128
    float* y1 = (float*)uW + 128;   // 64
    int t = tid;
    if (t < 64) {
      float sv = __hip_atomic_load(&a.gsum[t], __ATOMIC_RELAXED, __HIP_MEMORY_SCOPE_AGENT);
      g[t] = sv / (float)a.N;
    } else if (t < 128) {
      u32 k = __hip_atomic_load(&a.gmax[t - 64], __ATOMIC_RELAXED, __HIP_MEMORY_SCOPE_AGENT);
      u32 b = (k & 0x80000000u) ? (k & 0x7fffffffu) : ~k;
      g[t] = __uint_as_float(b);
    }
    __syncthreads();
    if (t < 64) {
      float acc = a.bg1[t];
      for (int i = 0; i < 128; i++) acc = fmaf(g[i], a.Wg1[i * 64 + t], acc);
      y1[t] = fmaxf(acc, 0.f);
    }
    __syncthreads();
    if (t < 64) {
      float acc = a.bg2[t];
      for (int k = 0; k < 64; k++) acc = fmaf(y1[k], a.Wg2[k * 64 + t], acc);
      a.out[t] = acc;
    }
  }
}

extern "C" void kernel_launch(void* const* d_in, const int* in_sizes, int n_in,
                              void* d_out, int out_size, void* d_ws, size_t ws_size,
                              hipStream_t stream) {
  const int N = in_sizes[0] / 256;
  const int E = in_sizes[1] / 4;

  // ws layout: [zeroed: bar(16) gsum(64) gmax(64) counts(N) agg(N*64)] cursor partial gfr tes hb
  char* ws = (char*)d_ws;
  u32*   bar    = (u32*)ws;                            // 16 u32
  float* gsum   = (float*)(bar + 16);                  // 64 f32
  u32*   gmax   = (u32*)(gsum + 64);                   // 64 u32
  u32*   counts = gmax + 64;                           // N u32
  float* agg    = (float*)(counts + N);                // N*64 f32
  size_t zeroB  = 64 + 256 + 256 + (size_t)N * 4 + (size_t)N * 64 * 4;
  u32*   cursor = (u32*)(agg + (size_t)N * 64);        // N u32
  u32*   partial = cursor + N;                         // NBLK u32
  u16*   gfr    = (u16*)(partial + NBLK);              // GF_TOT u16 (16B-aligned)
  uint4* tes    = (uint4*)(gfr + ((GF_TOT + 7) & ~7)); // E uint4
  u16*   hb     = (u16*)(tes + E);                     // N*64 bf16

  Args a;
  a.X = (const float*)d_in[0];  a.te = (const float*)d_in[1];
  a.W1 = (const float*)d_in[2]; a.b1 = (const float*)d_in[3];
  a.g1 = (const float*)d_in[4]; a.be1 = (const float*)d_in[5];
  a.W2 = (const float*)d_in[6]; a.b2 = (const float*)d_in[7];
  a.rel_emb = (const float*)d_in[8];
  a.Wm1 = (const float*)d_in[9]; a.bm1 = (const float*)d_in[10];
  a.Wm2 = (const float*)d_in[11]; a.bm2 = (const float*)d_in[12];
  a.gn = (const float*)d_in[13]; a.bn = (const float*)d_in[14];
  a.Wg1 = (const float*)d_in[15]; a.bg1 = (const float*)d_in[16];
  a.Wg2 = (const float*)d_in[17]; a.bg2 = (const float*)d_in[18];
  a.out = (float*)d_out;
  a.bar = bar; a.gsum = gsum; a.gmax = gmax; a.counts = counts; a.agg = agg;
  a.cursor = cursor; a.partial = partial; a.gfr = gfr; a.tes = tes; a.hb = hb;
  a.N = N; a.E = E;

  hipMemsetAsync(ws, 0, zeroB, stream);
  hipLaunchKernelGGL(k_mega, dim3(NBLK), dim3(256), 0, stream, a);
}

// Round 7
// 555.961 us; speedup vs baseline: 2.1783x; 2.1783x over previous
//
#include <hip/hip_runtime.h>

typedef unsigned short u16;
typedef unsigned int   u32;
typedef __attribute__((ext_vector_type(8))) short bf16x8;   // 8 bf16 (4 VGPRs)
typedef __attribute__((ext_vector_type(4))) float f32x4;    // mfma acc

#define EPS 1e-5f
#define MFMA(a,b,c) __builtin_amdgcn_mfma_f32_16x16x32_bf16(a,b,c,0,0,0)

__device__ __forceinline__ float bf2f(u32 u) { return __uint_as_float(u << 16); }
__device__ __forceinline__ u16 f2bf(float f) {
  u32 b = __float_as_uint(f);
  return (u16)((b + 0x7fffu + ((b >> 16) & 1u)) >> 16);  // RNE
}
__device__ __forceinline__ u32 fkey(float f) {  // monotone float->u32 (finite)
  u32 b = __float_as_uint(f);
  return (b & 0x80000000u) ? ~b : (b | 0x80000000u);
}

// Stage W (nchunks x 32 x 64 f32) coalesced into LDS, swizzle LDS->LDS into
// B-frag layout: sDst[(c*4+f)*512 + L*8 + j] = W[c*32+(L>>4)*8+j][(f&3)*16+(L&15)]
__device__ __forceinline__ void swizzle_stage(const float* __restrict__ W, int nchunks,
                                              u16* __restrict__ sDst, float* __restrict__ stage,
                                              int tid) {
  for (int c = 0; c < nchunks; c++) {
    __syncthreads();
    #pragma unroll
    for (int r2 = 0; r2 < 2; r2++) {
      int i = tid + r2 * 256;                       // 512 float4 = 2048 f32
      *(float4*)(stage + i * 4) = *(const float4*)(W + c * 2048 + i * 4);
    }
    __syncthreads();
    for (int idx = tid; idx < 2048; idx += 256) {
      int fl = idx >> 9, L = (idx >> 3) & 63, j = idx & 7;
      float val = stage[((((L >> 4) << 3) + j) << 6) + ((fl & 3) << 4) + (L & 15)];
      sDst[(c * 4 + fl) * 512 + L * 8 + j] = f2bf(val);
    }
  }
  __syncthreads();
}

// ---- k_h: zero agg/stats; h = relu(relu(LN(X@W1+b1))@W2+b2) -> bf16 ----
__launch_bounds__(256, 3)
__global__ void k_h(const float* __restrict__ X,
                    const float* __restrict__ W1, const float* __restrict__ b1,
                    const float* __restrict__ g1, const float* __restrict__ be1,
                    const float* __restrict__ W2, const float* __restrict__ b2,
                    float* __restrict__ zbase, u16* __restrict__ hb, int N) {
  __shared__ __align__(16) u16 sW1[32 * 512];     // 32 KB
  __shared__ __align__(16) u16 sW2[8 * 512];      // 8 KB
  __shared__ __align__(16) u16 st[4][1152];       // 9 KB (doubles as swizzle staging)

  // zero agg + gsum + gmax + done (N*16 + 48 float4s)
  {
    int gtid = blockIdx.x * 256 + threadIdx.x, nth = gridDim.x * 256;
    float4 z = make_float4(0.f, 0.f, 0.f, 0.f);
    int tot = N * 16 + 48;
    for (int i = gtid; i < tot; i += nth) ((float4*)zbase)[i] = z;
  }

  swizzle_stage(W1, 8, sW1, (float*)st, threadIdx.x);
  swizzle_stage(W2, 2, sW2, (float*)st, threadIdx.x);

  int lane = threadIdx.x & 63, wave = threadIdx.x >> 6;
  int m = lane & 15, quad = lane >> 4, koff = quad * 8, col0 = m;

  float b1v[4], g1v[4], be1v[4], b2v[4];
  #pragma unroll
  for (int nt = 0; nt < 4; nt++) {
    int c = nt * 16 + col0;
    b1v[nt] = b1[c]; g1v[nt] = g1[c]; be1v[nt] = be1[c]; b2v[nt] = b2[c];
  }

  int ntiles = (N + 15) / 16;
  int wid = blockIdx.x * 4 + wave, nw = gridDim.x * 4;
  for (int tile = wid; tile < ntiles; tile += nw) {
    int n0 = tile * 16;
    int nm = min(n0 + m, N - 1);
    const float* xr = X + (size_t)nm * 256 + koff;

    f32x4 acc[4] = {};
    #pragma unroll 4
    for (int ks = 0; ks < 8; ks++) {
      float4 u0 = *(const float4*)(xr + ks * 32);
      float4 u1 = *(const float4*)(xr + ks * 32 + 4);
      bf16x8 av;
      av[0] = (short)f2bf(u0.x); av[1] = (short)f2bf(u0.y);
      av[2] = (short)f2bf(u0.z); av[3] = (short)f2bf(u0.w);
      av[4] = (short)f2bf(u1.x); av[5] = (short)f2bf(u1.y);
      av[6] = (short)f2bf(u1.z); av[7] = (short)f2bf(u1.w);
      #pragma unroll
      for (int nt = 0; nt < 4; nt++) {
        bf16x8 b = *(const bf16x8*)(sW1 + (ks * 4 + nt) * 512 + lane * 8);
        acc[nt] = MFMA(av, b, acc[nt]);
      }
    }

    float v[4][4];
    #pragma unroll
    for (int nt = 0; nt < 4; nt++)
      #pragma unroll
      for (int r = 0; r < 4; r++) v[nt][r] = acc[nt][r] + b1v[nt];

    #pragma unroll
    for (int r = 0; r < 4; r++) {
      float s = v[0][r] + v[1][r] + v[2][r] + v[3][r];
      #pragma unroll
      for (int mk = 8; mk >= 1; mk >>= 1) s += __shfl_xor(s, mk, 64);
      float mu = s * (1.f / 64.f);
      float q = 0.f;
      #pragma unroll
      for (int nt = 0; nt < 4; nt++) { float d = v[nt][r] - mu; q += d * d; }
      #pragma unroll
      for (int mk = 8; mk >= 1; mk >>= 1) q += __shfl_xor(q, mk, 64);
      float rs = rsqrtf(q * (1.f / 64.f) + EPS);
      #pragma unroll
      for (int nt = 0; nt < 4; nt++) {
        float h1 = fmaxf(fmaf((v[nt][r] - mu) * rs, g1v[nt], be1v[nt]), 0.f);
        st[wave][(quad * 4 + r) * 72 + nt * 16 + col0] = f2bf(h1);
      }
    }
    __builtin_amdgcn_wave_barrier();

    f32x4 acc2[4] = {};
    #pragma unroll
    for (int ks = 0; ks < 2; ks++) {
      bf16x8 a2 = *(const bf16x8*)(st[wave] + m * 72 + ks * 32 + koff);
      #pragma unroll
      for (int nt = 0; nt < 4; nt++) {
        bf16x8 b = *(const bf16x8*)(sW2 + (ks * 4 + nt) * 512 + lane * 8);
        acc2[nt] = MFMA(a2, b, acc2[nt]);
      }
    }
    __builtin_amdgcn_wave_barrier();

    #pragma unroll
    for (int nt = 0; nt < 4; nt++)
      #pragma unroll
      for (int r = 0; r < 4; r++) {
        int row = n0 + quad * 4 + r;
        if (row < N)
          hb[(size_t)row * 64 + nt * 16 + col0] = f2bf(fmaxf(acc2[nt][r] + b2v[nt], 0.f));
      }
  }
}

// ---- k_edge: per-edge MLP (MFMA) + full-row coalesced atomics (2 line-ops/edge) ----
__launch_bounds__(256, 3)
__global__ void k_edge(const float* __restrict__ te, const u16* __restrict__ hb,
                       const float* __restrict__ Wm1, const float* __restrict__ bm1,
                       const float* __restrict__ Wm2, const float* __restrict__ bm2,
                       const float* __restrict__ rel_emb,
                       float* __restrict__ agg, int E, int N) {
  __shared__ __align__(16) u16 sWm1[24 * 512];    // 24 KB
  __shared__ __align__(16) u16 sWm2[8 * 512];     // 8 KB
  __shared__ __align__(16) u16 srel[576];         // 1.1 KB
  __shared__ __align__(16) u16 st[4][1152];       // 9 KB (doubles as staging)

  swizzle_stage(Wm1, 6, sWm1, (float*)st, threadIdx.x);
  swizzle_stage(Wm2, 2, sWm2, (float*)st, threadIdx.x);
  for (int idx = threadIdx.x; idx < 576; idx += 256) {
    int r = idx / 80, c = idx % 80;
    srel[idx] = (r < 7 && c < 64) ? f2bf(rel_emb[r * 64 + c]) : (u16)0;
  }
  __syncthreads();

  int lane = threadIdx.x & 63, wave = threadIdx.x >> 6;
  int m = lane & 15, quad = lane >> 4, koff = quad * 8, col0 = m;

  float bm1v[4], w192v[4], bm2v[4];
  #pragma unroll
  for (int nt = 0; nt < 4; nt++) {
    int c = nt * 16 + col0;
    bm1v[nt] = bm1[c];
    w192v[nt] = Wm1[192 * 64 + c];
    bm2v[nt] = bm2[c];
  }

  int ntiles = (E + 15) / 16;
  int wid = blockIdx.x * 4 + wave, nw = gridDim.x * 4;
  for (int tile = wid; tile < ntiles; tile += nw) {
    int e0 = tile * 16;
    int src = 0, dstc = 0, rel = 0; float w = 0.f;
    if (lane < 16) {
      int e = min(e0 + lane, E - 1);
      float4 v = *(const float4*)(te + (size_t)e * 4);
      src = min(max((int)v.x, 0), N - 1);
      dstc = min(max((int)v.y, 0), N - 1);
      rel = min(max((int)v.z, 0), 6);
      w = v.w;
    }
    int src_m = __shfl(src, m, 64);
    int dst_m = __shfl(dstc, m, 64);
    int rel_m = __shfl(rel, m, 64);

    const u16* hs = hb + (size_t)src_m * 64;
    const u16* hd = hb + (size_t)dst_m * 64;
    bf16x8 af[6];
    af[0] = *(const bf16x8*)(hs + koff);
    af[1] = *(const bf16x8*)(hs + 32 + koff);
    af[2] = *(const bf16x8*)(hd + koff);
    af[3] = *(const bf16x8*)(hd + 32 + koff);
    af[4] = *(const bf16x8*)(srel + rel_m * 80 + koff);
    af[5] = *(const bf16x8*)(srel + rel_m * 80 + 32 + koff);

    f32x4 acc[4] = {};
    #pragma unroll
    for (int ks = 0; ks < 6; ks++) {
      #pragma unroll
      for (int nt = 0; nt < 4; nt++) {
        bf16x8 b = *(const bf16x8*)(sWm1 + (ks * 4 + nt) * 512 + lane * 8);
        acc[nt] = MFMA(af[ks], b, acc[nt]);
      }
    }

    // epilogue 1: + bm1 + w*Wm1[192], relu, t -> LDS bf16
    float wrow[4];
    #pragma unroll
    for (int r = 0; r < 4; r++) wrow[r] = __shfl(w, quad * 4 + r, 64);
    #pragma unroll
    for (int nt = 0; nt < 4; nt++)
      #pragma unroll
      for (int r = 0; r < 4; r++) {
        float v = fmaf(wrow[r], w192v[nt], acc[nt][r] + bm1v[nt]);
        st[wave][(quad * 4 + r) * 72 + nt * 16 + col0] = f2bf(fmaxf(v, 0.f));
      }
    __builtin_amdgcn_wave_barrier();

    f32x4 acc2[4] = {};
    #pragma unroll
    for (int ks = 0; ks < 2; ks++) {
      bf16x8 a2 = *(const bf16x8*)(st[wave] + m * 72 + ks * 32 + koff);
      #pragma unroll
      for (int nt = 0; nt < 4; nt++) {
        bf16x8 b = *(const bf16x8*)(sWm2 + (ks * 4 + nt) * 512 + lane * 8);
        acc2[nt] = MFMA(a2, b, acc2[nt]);
      }
    }
    __builtin_amdgcn_wave_barrier();

    // msg rows (+bm2) -> st (bf16), row-major
    #pragma unroll
    for (int nt = 0; nt < 4; nt++)
      #pragma unroll
      for (int r = 0; r < 4; r++)
        st[wave][(quad * 4 + r) * 72 + nt * 16 + col0] = f2bf(acc2[nt][r] + bm2v[nt]);
    __builtin_amdgcn_wave_barrier();

    // scatter: one wave-atomic per edge covering its full 64-col row (256B = 2 lines)
    #pragma unroll 1
    for (int r = 0; r < 16; r++) {
      if (e0 + r < E) {
        int d = __shfl(dstc, r, 64);
        atomicAdd(agg + (size_t)d * 64 + lane, bf2f(st[wave][r * 72 + lane]));
      }
    }
    __builtin_amdgcn_wave_barrier();
  }
}

// ---- k_nodes: LN(h+agg); column sum+max; last block runs final MLP ----
__launch_bounds__(256)
__global__ void k_nodes(const u16* __restrict__ hb, const float* __restrict__ agg,
                        const float* __restrict__ gn, const float* __restrict__ bn,
                        const float* __restrict__ Wg1, const float* __restrict__ bg1,
                        const float* __restrict__ Wg2, const float* __restrict__ bg2,
                        float* __restrict__ gsum, u32* __restrict__ gmax,
                        u32* __restrict__ done, float* __restrict__ out, int N) {
  int lane = threadIdx.x & 63, wave = threadIdx.x >> 6;
  int wid = blockIdx.x * 4 + wave;
  int nw = gridDim.x * 4;
  float gnv = gn[lane], bnv = bn[lane];
  float sj = 0.f, mj = -3.0e38f;
  for (int n = wid; n < N; n += nw) {
    float v = bf2f(hb[(size_t)n * 64 + lane]) + agg[(size_t)n * 64 + lane];
    float s = v;
    #pragma unroll
    for (int mk = 32; mk >= 1; mk >>= 1) s += __shfl_xor(s, mk, 64);
    float mu = s * (1.f / 64.f);
    float d = v - mu;
    float q = d * d;
    #pragma unroll
    for (int mk = 32; mk >= 1; mk >>= 1) q += __shfl_xor(q, mk, 64);
    float rs = rsqrtf(q * (1.f / 64.f) + EPS);
    float val = fmaf(d * rs, gnv, bnv);
    sj += val;
    mj = fmaxf(mj, val);
  }
  __shared__ float bs[256], bm[256];
  bs[threadIdx.x] = sj;
  bm[threadIdx.x] = mj;
  __syncthreads();
  if (threadIdx.x < 64) {
    int t = threadIdx.x;
    float ts = bs[t] + bs[64 + t] + bs[128 + t] + bs[192 + t];
    float tm = fmaxf(fmaxf(bm[t], bm[64 + t]), fmaxf(bm[128 + t], bm[192 + t]));
    atomicAdd(gsum + t, ts);
    atomicMax(gmax + t, fkey(tm));
  }

  __threadfence();
  __shared__ u32 lastv;
  if (threadIdx.x == 0) lastv = atomicAdd(done, 1u);
  __syncthreads();
  if (lastv == gridDim.x - 1) {
    __shared__ float g[128];
    __shared__ float y1[64];
    int t = threadIdx.x;
    if (t < 64) {
      float sv = __hip_atomic_load(&gsum[t], __ATOMIC_RELAXED, __HIP_MEMORY_SCOPE_AGENT);
      g[t] = sv / (float)N;
    } else if (t < 128) {
      u32 k = __hip_atomic_load(&gmax[t - 64], __ATOMIC_RELAXED, __HIP_MEMORY_SCOPE_AGENT);
      u32 b = (k & 0x80000000u) ? (k & 0x7fffffffu) : ~k;
      g[t] = __uint_as_float(b);
    }
    __syncthreads();
    if (t < 64) {
      float a = bg1[t];
      for (int i = 0; i < 128; i++) a = fmaf(g[i], Wg1[i * 64 + t], a);
      y1[t] = fmaxf(a, 0.f);
    }
    __syncthreads();
    if (t < 64) {
      float a = bg2[t];
      for (int k = 0; k < 64; k++) a = fmaf(y1[k], Wg2[k * 64 + t], a);
      out[t] = a;
    }
  }
}

extern "C" void kernel_launch(void* const* d_in, const int* in_sizes, int n_in,
                              void* d_out, int out_size, void* d_ws, size_t ws_size,
                              hipStream_t stream) {
  const int N = in_sizes[0] / 256;
  const int E = in_sizes[1] / 4;

  // ws layout (agg..done zeroed by k_h phase 0): agg | gsum | gmax | done | hb
  float* agg  = (float*)d_ws;                    // N*64 f32
  float* gsum = agg + (size_t)N * 64;            // 64 f32
  u32*   gmax = (u32*)(gsum + 64);               // 64 u32
  u32*   done = gmax + 64;                       // 64 u32 (1 used)
  u16*   hb   = (u16*)(done + 64);               // N*64 bf16

  const float* X  = (const float*)d_in[0];
  const float* te = (const float*)d_in[1];

  hipLaunchKernelGGL(k_h, dim3(800), dim3(256), 0, stream, X,
                     (const float*)d_in[2], (const float*)d_in[3], (const float*)d_in[4],
                     (const float*)d_in[5], (const float*)d_in[6], (const float*)d_in[7],
                     agg, hb, N);
  hipLaunchKernelGGL(k_edge, dim3(768), dim3(256), 0, stream, te, hb,
                     (const float*)d_in[9], (const float*)d_in[10],
                     (const float*)d_in[11], (const float*)d_in[12],
                     (const float*)d_in[8], agg, E, N);
  hipLaunchKernelGGL(k_nodes, dim3(2048), dim3(256), 0, stream, hb, agg,
                     (const float*)d_in[13], (const float*)d_in[14],
                     (const float*)d_in[15], (const float*)d_in[16],
                     (const float*)d_in[17], (const float*)d_in[18],
                     gsum, gmax, done, (float*)d_out, N);
}

// Round 8
// 468.132 us; speedup vs baseline: 2.5870x; 1.1876x over previous
//
#include <hip/hip_runtime.h>

typedef unsigned short u16;
typedef unsigned int   u32;
typedef __attribute__((ext_vector_type(8))) short bf16x8;   // 8 bf16 (4 VGPRs)
typedef __attribute__((ext_vector_type(4))) float f32x4;    // mfma acc

#define EPS 1e-5f
#define MFMA(a,b,c) __builtin_amdgcn_mfma_f32_16x16x32_bf16(a,b,c,0,0,0)

__device__ __forceinline__ float bf2f(u32 u) { return __uint_as_float(u << 16); }
__device__ __forceinline__ u16 f2bf(float f) {
  u32 b = __float_as_uint(f);
  return (u16)((b + 0x7fffu + ((b >> 16) & 1u)) >> 16);  // RNE
}
__device__ __forceinline__ u32 fkey(float f) {  // monotone float->u32 (finite)
  u32 b = __float_as_uint(f);
  return (b & 0x80000000u) ? ~b : (b | 0x80000000u);
}

// Stage W (nchunks x 32 x 64 f32) coalesced into LDS, swizzle LDS->LDS into
// B-frag layout: sDst[(c*4+f)*512 + L*8 + j] = W[c*32+(L>>4)*8+j][(f&3)*16+(L&15)]
__device__ __forceinline__ void swizzle_stage(const float* __restrict__ W, int nchunks,
                                              u16* __restrict__ sDst, float* __restrict__ stage,
                                              int tid) {
  for (int c = 0; c < nchunks; c++) {
    __syncthreads();
    #pragma unroll
    for (int r2 = 0; r2 < 2; r2++) {
      int i = tid + r2 * 256;                       // 512 float4 = 2048 f32
      *(float4*)(stage + i * 4) = *(const float4*)(W + c * 2048 + i * 4);
    }
    __syncthreads();
    for (int idx = tid; idx < 2048; idx += 256) {
      int fl = idx >> 9, L = (idx >> 3) & 63, j = idx & 7;
      float val = stage[((((L >> 4) << 3) + j) << 6) + ((fl & 3) << 4) + (L & 15)];
      sDst[(c * 4 + fl) * 512 + L * 8 + j] = f2bf(val);
    }
  }
  __syncthreads();
}

// ---- k_h: zero agg/stats; h = relu(relu(LN(X@W1+b1))@W2+b2) -> bf16 ----
__launch_bounds__(256, 3)
__global__ void k_h(const float* __restrict__ X,
                    const float* __restrict__ W1, const float* __restrict__ b1,
                    const float* __restrict__ g1, const float* __restrict__ be1,
                    const float* __restrict__ W2, const float* __restrict__ b2,
                    float* __restrict__ zbase, u16* __restrict__ hb, int N) {
  __shared__ __align__(16) u16 sW1[32 * 512];     // 32 KB
  __shared__ __align__(16) u16 sW2[8 * 512];      // 8 KB
  __shared__ __align__(16) u16 st[4][1152];       // 9 KB (doubles as swizzle staging)

  // zero agg + gsum + gmax + done (N*16 + 48 float4s)
  {
    int gtid = blockIdx.x * 256 + threadIdx.x, nth = gridDim.x * 256;
    float4 z = make_float4(0.f, 0.f, 0.f, 0.f);
    int tot = N * 16 + 48;
    for (int i = gtid; i < tot; i += nth) ((float4*)zbase)[i] = z;
  }

  swizzle_stage(W1, 8, sW1, (float*)st, threadIdx.x);
  swizzle_stage(W2, 2, sW2, (float*)st, threadIdx.x);

  int lane = threadIdx.x & 63, wave = threadIdx.x >> 6;
  int m = lane & 15, quad = lane >> 4, koff = quad * 8, col0 = m;

  float b1v[4], g1v[4], be1v[4], b2v[4];
  #pragma unroll
  for (int nt = 0; nt < 4; nt++) {
    int c = nt * 16 + col0;
    b1v[nt] = b1[c]; g1v[nt] = g1[c]; be1v[nt] = be1[c]; b2v[nt] = b2[c];
  }

  int ntiles = (N + 15) / 16;
  int wid = blockIdx.x * 4 + wave, nw = gridDim.x * 4;
  for (int tile = wid; tile < ntiles; tile += nw) {
    int n0 = tile * 16;
    int nm = min(n0 + m, N - 1);
    const float* xr = X + (size_t)nm * 256 + koff;

    f32x4 acc[4] = {};
    #pragma unroll 4
    for (int ks = 0; ks < 8; ks++) {
      float4 u0 = *(const float4*)(xr + ks * 32);
      float4 u1 = *(const float4*)(xr + ks * 32 + 4);
      bf16x8 av;
      av[0] = (short)f2bf(u0.x); av[1] = (short)f2bf(u0.y);
      av[2] = (short)f2bf(u0.z); av[3] = (short)f2bf(u0.w);
      av[4] = (short)f2bf(u1.x); av[5] = (short)f2bf(u1.y);
      av[6] = (short)f2bf(u1.z); av[7] = (short)f2bf(u1.w);
      #pragma unroll
      for (int nt = 0; nt < 4; nt++) {
        bf16x8 b = *(const bf16x8*)(sW1 + (ks * 4 + nt) * 512 + lane * 8);
        acc[nt] = MFMA(av, b, acc[nt]);
      }
    }

    float v[4][4];
    #pragma unroll
    for (int nt = 0; nt < 4; nt++)
      #pragma unroll
      for (int r = 0; r < 4; r++) v[nt][r] = acc[nt][r] + b1v[nt];

    #pragma unroll
    for (int r = 0; r < 4; r++) {
      float s = v[0][r] + v[1][r] + v[2][r] + v[3][r];
      #pragma unroll
      for (int mk = 8; mk >= 1; mk >>= 1) s += __shfl_xor(s, mk, 64);
      float mu = s * (1.f / 64.f);
      float q = 0.f;
      #pragma unroll
      for (int nt = 0; nt < 4; nt++) { float d = v[nt][r] - mu; q += d * d; }
      #pragma unroll
      for (int mk = 8; mk >= 1; mk >>= 1) q += __shfl_xor(q, mk, 64);
      float rs = rsqrtf(q * (1.f / 64.f) + EPS);
      #pragma unroll
      for (int nt = 0; nt < 4; nt++) {
        float h1 = fmaxf(fmaf((v[nt][r] - mu) * rs, g1v[nt], be1v[nt]), 0.f);
        st[wave][(quad * 4 + r) * 72 + nt * 16 + col0] = f2bf(h1);
      }
    }
    __builtin_amdgcn_wave_barrier();

    f32x4 acc2[4] = {};
    #pragma unroll
    for (int ks = 0; ks < 2; ks++) {
      bf16x8 a2 = *(const bf16x8*)(st[wave] + m * 72 + ks * 32 + koff);
      #pragma unroll
      for (int nt = 0; nt < 4; nt++) {
        bf16x8 b = *(const bf16x8*)(sW2 + (ks * 4 + nt) * 512 + lane * 8);
        acc2[nt] = MFMA(a2, b, acc2[nt]);
      }
    }
    __builtin_amdgcn_wave_barrier();

    #pragma unroll
    for (int nt = 0; nt < 4; nt++)
      #pragma unroll
      for (int r = 0; r < 4; r++) {
        int row = n0 + quad * 4 + r;
        if (row < N)
          hb[(size_t)row * 64 + nt * 16 + col0] = f2bf(fmaxf(acc2[nt][r] + b2v[nt], 0.f));
      }
  }
}

// ---- k_edge: per-edge MLP (MFMA) + direct-from-register coalesced atomics ----
__launch_bounds__(256, 3)
__global__ void k_edge(const float* __restrict__ te, const u16* __restrict__ hb,
                       const float* __restrict__ Wm1, const float* __restrict__ bm1,
                       const float* __restrict__ Wm2, const float* __restrict__ bm2,
                       const float* __restrict__ rel_emb,
                       float* __restrict__ agg, int E, int N) {
  __shared__ __align__(16) u16 sWm1[24 * 512];    // 24 KB
  __shared__ __align__(16) u16 sWm2[8 * 512];     // 8 KB
  __shared__ __align__(16) u16 srel[576];         // 1.1 KB
  __shared__ __align__(16) u16 st[4][1152];       // 9 KB (doubles as staging)

  swizzle_stage(Wm1, 6, sWm1, (float*)st, threadIdx.x);
  swizzle_stage(Wm2, 2, sWm2, (float*)st, threadIdx.x);
  for (int idx = threadIdx.x; idx < 576; idx += 256) {
    int r = idx / 80, c = idx % 80;
    srel[idx] = (r < 7 && c < 64) ? f2bf(rel_emb[r * 64 + c]) : (u16)0;
  }
  __syncthreads();

  int lane = threadIdx.x & 63, wave = threadIdx.x >> 6;
  int m = lane & 15, quad = lane >> 4, koff = quad * 8, col0 = m;

  float bm1v[4], w192v[4], bm2v[4];
  #pragma unroll
  for (int nt = 0; nt < 4; nt++) {
    int c = nt * 16 + col0;
    bm1v[nt] = bm1[c];
    w192v[nt] = Wm1[192 * 64 + c];
    bm2v[nt] = bm2[c];
  }

  int ntiles = (E + 15) / 16;
  int wid = blockIdx.x * 4 + wave, nw = gridDim.x * 4;
  for (int tile = wid; tile < ntiles; tile += nw) {
    int e0 = tile * 16;
    int src = 0, dstc = 0, rel = 0; float w = 0.f;
    if (lane < 16) {
      int e = min(e0 + lane, E - 1);
      float4 v = *(const float4*)(te + (size_t)e * 4);
      src = min(max((int)v.x, 0), N - 1);
      dstc = min(max((int)v.y, 0), N - 1);
      rel = min(max((int)v.z, 0), 6);
      w = v.w;
    }
    int src_m = __shfl(src, m, 64);
    int dst_m = __shfl(dstc, m, 64);
    int rel_m = __shfl(rel, m, 64);

    const u16* hs = hb + (size_t)src_m * 64;
    const u16* hd = hb + (size_t)dst_m * 64;
    bf16x8 af[6];
    af[0] = *(const bf16x8*)(hs + koff);
    af[1] = *(const bf16x8*)(hs + 32 + koff);
    af[2] = *(const bf16x8*)(hd + koff);
    af[3] = *(const bf16x8*)(hd + 32 + koff);
    af[4] = *(const bf16x8*)(srel + rel_m * 80 + koff);
    af[5] = *(const bf16x8*)(srel + rel_m * 80 + 32 + koff);

    f32x4 acc[4] = {};
    #pragma unroll
    for (int ks = 0; ks < 6; ks++) {
      #pragma unroll
      for (int nt = 0; nt < 4; nt++) {
        bf16x8 b = *(const bf16x8*)(sWm1 + (ks * 4 + nt) * 512 + lane * 8);
        acc[nt] = MFMA(af[ks], b, acc[nt]);
      }
    }

    // epilogue 1: + bm1 + w*Wm1[192], relu, t -> LDS bf16
    float wrow[4];
    #pragma unroll
    for (int r = 0; r < 4; r++) wrow[r] = __shfl(w, quad * 4 + r, 64);
    #pragma unroll
    for (int nt = 0; nt < 4; nt++)
      #pragma unroll
      for (int r = 0; r < 4; r++) {
        float v = fmaf(wrow[r], w192v[nt], acc[nt][r] + bm1v[nt]);
        st[wave][(quad * 4 + r) * 72 + nt * 16 + col0] = f2bf(fmaxf(v, 0.f));
      }
    __builtin_amdgcn_wave_barrier();

    f32x4 acc2[4] = {};
    #pragma unroll
    for (int ks = 0; ks < 2; ks++) {
      bf16x8 a2 = *(const bf16x8*)(st[wave] + m * 72 + ks * 32 + koff);
      #pragma unroll
      for (int nt = 0; nt < 4; nt++) {
        bf16x8 b = *(const bf16x8*)(sWm2 + (ks * 4 + nt) * 512 + lane * 8);
        acc2[nt] = MFMA(a2, b, acc2[nt]);
      }
    }
    __builtin_amdgcn_wave_barrier();

    // scatter: + bm2, direct from registers (4 edge-rows x 16 cols per instr)
    int dstr[4]; bool valr[4];
    #pragma unroll
    for (int r = 0; r < 4; r++) {
      int row = quad * 4 + r;
      dstr[r] = __shfl(dstc, row, 64);
      valr[r] = (e0 + row) < E;
    }
    #pragma unroll
    for (int nt = 0; nt < 4; nt++)
      #pragma unroll
      for (int r = 0; r < 4; r++)
        if (valr[r])
          atomicAdd(agg + (size_t)dstr[r] * 64 + nt * 16 + col0, acc2[nt][r] + bm2v[nt]);
  }
}

// ---- k_nodes: nodes = LN(h+agg); global column sum + max (plain, no fence) ----
__launch_bounds__(256)
__global__ void k_nodes(const u16* __restrict__ hb, const float* __restrict__ agg,
                        const float* __restrict__ gn, const float* __restrict__ bn,
                        float* __restrict__ gsum, u32* __restrict__ gmax, int N) {
  int lane = threadIdx.x & 63, wave = threadIdx.x >> 6;
  int wid = blockIdx.x * 4 + wave;
  int nw = gridDim.x * 4;
  float gnv = gn[lane], bnv = bn[lane];
  float sj = 0.f, mj = -3.0e38f;
  for (int n = wid; n < N; n += nw) {
    float v = bf2f(hb[(size_t)n * 64 + lane]) + agg[(size_t)n * 64 + lane];
    float s = v;
    #pragma unroll
    for (int mk = 32; mk >= 1; mk >>= 1) s += __shfl_xor(s, mk, 64);
    float mu = s * (1.f / 64.f);
    float d = v - mu;
    float q = d * d;
    #pragma unroll
    for (int mk = 32; mk >= 1; mk >>= 1) q += __shfl_xor(q, mk, 64);
    float rs = rsqrtf(q * (1.f / 64.f) + EPS);
    float val = fmaf(d * rs, gnv, bnv);
    sj += val;
    mj = fmaxf(mj, val);
  }
  __shared__ float bs[256], bm[256];
  bs[threadIdx.x] = sj;
  bm[threadIdx.x] = mj;
  __syncthreads();
  if (threadIdx.x < 64) {
    int t = threadIdx.x;
    float ts = bs[t] + bs[64 + t] + bs[128 + t] + bs[192 + t];
    float tm = fmaxf(fmaxf(bm[t], bm[64 + t]), fmaxf(bm[128 + t], bm[192 + t]));
    atomicAdd(gsum + t, ts);
    atomicMax(gmax + t, fkey(tm));
  }
}

// ---- k_final: g=[mean,max]; out = relu(g@Wg1+bg1)@Wg2+bg2 ----
__launch_bounds__(128)
__global__ void k_final(const float* __restrict__ gsum, const u32* __restrict__ gmax,
                        const float* __restrict__ Wg1, const float* __restrict__ bg1,
                        const float* __restrict__ Wg2, const float* __restrict__ bg2,
                        float* __restrict__ out, int N) {
  __shared__ float g[128];
  __shared__ float y1[64];
  int t = threadIdx.x;
  if (t < 64) {
    g[t] = gsum[t] / (float)N;
  } else {
    u32 k = gmax[t - 64];
    u32 b = (k & 0x80000000u) ? (k & 0x7fffffffu) : ~k;
    g[t] = __uint_as_float(b);
  }
  __syncthreads();
  if (t < 64) {
    float a = bg1[t];
    for (int i = 0; i < 128; i++) a = fmaf(g[i], Wg1[i * 64 + t], a);
    y1[t] = fmaxf(a, 0.f);
  }
  __syncthreads();
  if (t < 64) {
    float a = bg2[t];
    for (int k = 0; k < 64; k++) a = fmaf(y1[k], Wg2[k * 64 + t], a);
    out[t] = a;
  }
}

extern "C" void kernel_launch(void* const* d_in, const int* in_sizes, int n_in,
                              void* d_out, int out_size, void* d_ws, size_t ws_size,
                              hipStream_t stream) {
  const int N = in_sizes[0] / 256;
  const int E = in_sizes[1] / 4;

  // ws layout (agg..done zeroed by k_h phase 0): agg | gsum | gmax | pad | hb
  float* agg  = (float*)d_ws;                    // N*64 f32
  float* gsum = agg + (size_t)N * 64;            // 64 f32
  u32*   gmax = (u32*)(gsum + 64);               // 64 u32
  u32*   pad  = gmax + 64;                       // 64 u32
  u16*   hb   = (u16*)(pad + 64);                // N*64 bf16

  const float* X  = (const float*)d_in[0];
  const float* te = (const float*)d_in[1];

  hipLaunchKernelGGL(k_h, dim3(800), dim3(256), 0, stream, X,
                     (const float*)d_in[2], (const float*)d_in[3], (const float*)d_in[4],
                     (const float*)d_in[5], (const float*)d_in[6], (const float*)d_in[7],
                     agg, hb, N);
  hipLaunchKernelGGL(k_edge, dim3(768), dim3(256), 0, stream, te, hb,
                     (const float*)d_in[9], (const float*)d_in[10],
                     (const float*)d_in[11], (const float*)d_in[12],
                     (const float*)d_in[8], agg, E, N);
  hipLaunchKernelGGL(k_nodes, dim3(2048), dim3(256), 0, stream, hb, agg,
                     (const float*)d_in[13], (const float*)d_in[14],
                     gsum, gmax, N);
  hipLaunchKernelGGL(k_final, dim3(1), dim3(128), 0, stream, gsum, gmax,
                     (const float*)d_in[15], (const float*)d_in[16],
                     (const float*)d_in[17], (const float*)d_in[18],
                     (float*)d_out, N);
}